// Round 1
// baseline (920.952 us; speedup 1.0000x reference)
//
#include <hip/hip_runtime.h>
#include <hip/hip_bf16.h>

#define E      100
#define NSLOT  20
#define BB     512
#define TT     1005
#define NFULL  100
#define LL     10
#define REST   5
#define VV     32000

// ---------------------------------------------------------------------------
// Phase 1: infos (s_all, t-major), sW_all = infos @ W_w^T, q_all
// One block per b. Memory-bound (reads all of in_data).
// ---------------------------------------------------------------------------
__global__ __launch_bounds__(256, 2) void k_prep(
    const float* __restrict__ in_data, const float* __restrict__ f,
    const float* __restrict__ W_w,
    float* __restrict__ s_all, float* __restrict__ sW_all, float* __restrict__ q_all)
{
    __shared__ float Wt[E * E];   // Wt[e][fc] = W_w[fc][e]  (conflict-free reads)
    __shared__ float f_l[LL * E];
    __shared__ float s_l[2 * E];
    const int tid = threadIdx.x;
    const int b   = blockIdx.x;

    for (int idx = tid; idx < E * E; idx += 256) {
        int r = idx / E, e = idx % E;
        Wt[e * E + r] = W_w[r * E + e];
    }
    for (int idx = tid; idx < LL * E; idx += 256) f_l[idx] = f[idx];
    __syncthreads();

    const size_t base = (size_t)b * TT * E;
    for (int n = 0; n < NFULL; n += 2) {
        if (tid < 2 * E) {
            int e = tid % E, w = tid / E;
            int nn = n + w;
            float a = 0.f;
            #pragma unroll
            for (int l = 0; l < LL; ++l)
                a += f_l[l * E + e] * in_data[base + (size_t)(nn * LL + l) * E + e];
            s_l[w * E + e] = a;
            s_all[((size_t)nn * BB + b) * E + e] = a;
        }
        __syncthreads();
        if (tid < 2 * E) {
            int fc = tid % E, w = tid / E;
            float a = 0.f;
            for (int e = 0; e < E; ++e) a += Wt[e * E + fc] * s_l[w * E + e];
            sW_all[((size_t)(n + w) * BB + b) * E + fc] = a;
        }
        __syncthreads();
    }
    if (tid < E) {
        float a = 0.f;
        #pragma unroll
        for (int l = 0; l < REST; ++l)
            a += f_l[l * E + tid] * in_data[base + (size_t)(NFULL * LL + l) * E + tid];
        q_all[(size_t)b * E + tid] = a;
    }
}

// ---------------------------------------------------------------------------
// Phase 2: the recurrent scan. One block per b; 10240 independent (b,n)
// chains; 100 sequential steps inside the block. fp32 vector ALU.
// Thread tile: 2 n x 4 f per thread (250 active threads cover 20x100).
// ---------------------------------------------------------------------------
__global__ __launch_bounds__(256, 2) void k_scan(
    const float* __restrict__ h0, const float* __restrict__ w_mem,
    const float* __restrict__ U_w, const float* __restrict__ V_w,
    const float* __restrict__ a_dm,
    const float* __restrict__ s_all, const float* __restrict__ sW_all,
    float* __restrict__ h_final)
{
    __shared__ __align__(16) float Ut[E * E];    // first V_w^T, then U_w^T
    __shared__ float wm[NSLOT * E];
    __shared__ __align__(16) float hbuf[NSLOT * E];
    __shared__ __align__(16) float sv[E];
    __shared__ __align__(16) float swv[E];
    __shared__ float part[NSLOT * 25];
    __shared__ float gl[NSLOT], rn[NSLOT];

    const int tid = threadIdx.x;
    const int b   = blockIdx.x;
    const float adm = a_dm[0];

    // V_w^T into Ut (temporarily)
    for (int idx = tid; idx < E * E; idx += 256) {
        int r = idx / E, e = idx % E;
        Ut[e * E + r] = V_w[r * E + e];
    }
    for (int idx = tid; idx < NSLOT * E; idx += 256) {
        wm[idx]   = w_mem[idx];
        hbuf[idx] = h0[idx];
    }
    __syncthreads();

    const int fg = tid % 25;   // f-group: 4 consecutive f
    const int ng = tid / 25;   // n-group: 2 consecutive n (valid for tid<250)
    const int f0 = fg * 4;
    const int n0 = ng * 2;
    const bool act = (tid < 250);

    // Vw[n][f] = sum_e w_mem[n][e] * V_w[f][e]  -> registers (constant over t)
    float vw[2][4] = {};
    if (act) {
        #pragma unroll
        for (int i = 0; i < 2; ++i) {
            float a0 = 0.f, a1 = 0.f, a2 = 0.f, a3 = 0.f;
            for (int e = 0; e < E; ++e) {
                float w = wm[(n0 + i) * E + e];
                const float4 v = *reinterpret_cast<const float4*>(&Ut[e * E + f0]);
                a0 += w * v.x; a1 += w * v.y; a2 += w * v.z; a3 += w * v.w;
            }
            vw[i][0] = a0; vw[i][1] = a1; vw[i][2] = a2; vw[i][3] = a3;
        }
    }
    __syncthreads();
    // now U_w^T into Ut
    for (int idx = tid; idx < E * E; idx += 256) {
        int r = idx / E, e = idx % E;
        Ut[e * E + r] = U_w[r * E + e];
    }
    __syncthreads();

    for (int t = 0; t < NFULL; ++t) {
        if (tid < E)
            sv[tid] = s_all[((size_t)t * BB + b) * E + tid];
        else if (tid >= 128 && tid < 128 + E)
            swv[tid - 128] = sW_all[((size_t)t * BB + b) * E + (tid - 128)];
        __syncthreads();

        // gate dot: d[n] = sum_e (h[n][e]+wm[n][e]) * s[e]
        if (tid < 200) {
            int n = tid / 10, j = tid % 10;
            float a = 0.f;
            #pragma unroll
            for (int k = 0; k < 10; ++k) {
                int e = j * 10 + k;
                a += (hbuf[n * E + e] + wm[n * E + e]) * sv[e];
            }
            part[n * 10 + j] = a;
        }
        __syncthreads();
        if (tid < NSLOT) {
            float d = 0.f;
            #pragma unroll
            for (int j = 0; j < 10; ++j) d += part[tid * 10 + j];
            gl[tid] = 1.f / (1.f + expf(-d));
        }
        __syncthreads();

        // cand = prelu(U@h + Vw + sW);  hn = h + g*cand
        float hn[2][4];
        if (act) {
            float acc[2][4];
            const float4 s4 = *reinterpret_cast<const float4*>(&swv[f0]);
            #pragma unroll
            for (int i = 0; i < 2; ++i) {
                acc[i][0] = vw[i][0] + s4.x; acc[i][1] = vw[i][1] + s4.y;
                acc[i][2] = vw[i][2] + s4.z; acc[i][3] = vw[i][3] + s4.w;
            }
            #pragma unroll 4
            for (int e = 0; e < E; ++e) {
                const float4 u = *reinterpret_cast<const float4*>(&Ut[e * E + f0]);
                const float ha = hbuf[n0 * E + e];
                const float hb = hbuf[(n0 + 1) * E + e];
                acc[0][0] += u.x * ha; acc[0][1] += u.y * ha;
                acc[0][2] += u.z * ha; acc[0][3] += u.w * ha;
                acc[1][0] += u.x * hb; acc[1][1] += u.y * hb;
                acc[1][2] += u.z * hb; acc[1][3] += u.w * hb;
            }
            #pragma unroll
            for (int i = 0; i < 2; ++i) {
                const float g = gl[n0 + i];
                const float4 ho = *reinterpret_cast<const float4*>(&hbuf[(n0 + i) * E + f0]);
                float c0 = acc[i][0]; c0 = c0 >= 0.f ? c0 : adm * c0; hn[i][0] = ho.x + g * c0;
                float c1 = acc[i][1]; c1 = c1 >= 0.f ? c1 : adm * c1; hn[i][1] = ho.y + g * c1;
                float c2 = acc[i][2]; c2 = c2 >= 0.f ? c2 : adm * c2; hn[i][2] = ho.z + g * c2;
                float c3 = acc[i][3]; c3 = c3 >= 0.f ? c3 : adm * c3; hn[i][3] = ho.w + g * c3;
                part[(n0 + i) * 25 + fg] = hn[i][0]*hn[i][0] + hn[i][1]*hn[i][1]
                                         + hn[i][2]*hn[i][2] + hn[i][3]*hn[i][3];
            }
        }
        __syncthreads();
        if (tid < NSLOT) {
            float ss = 0.f;
            #pragma unroll
            for (int k = 0; k < 25; ++k) ss += part[tid * 25 + k];
            rn[tid] = 1.f / sqrtf(ss);
        }
        __syncthreads();
        if (act) {
            #pragma unroll
            for (int i = 0; i < 2; ++i) {
                const float r = rn[n0 + i];
                float4 o;
                o.x = hn[i][0] * r; o.y = hn[i][1] * r;
                o.z = hn[i][2] * r; o.w = hn[i][3] * r;
                *reinterpret_cast<float4*>(&hbuf[(n0 + i) * E + f0]) = o;
            }
        }
        __syncthreads();
    }

    for (int idx = tid; idx < NSLOT * E; idx += 256)
        h_final[(size_t)b * NSLOT * E + idx] = hbuf[idx];
}

// ---------------------------------------------------------------------------
// Phase 3: attention over entities + y -> prelu(y) (py_all). One block per b.
// ---------------------------------------------------------------------------
__global__ __launch_bounds__(128, 2) void k_attn(
    const float* __restrict__ h_final, const float* __restrict__ q_all,
    const float* __restrict__ H_w, const float* __restrict__ H_b,
    const float* __restrict__ a_out, float* __restrict__ py_all)
{
    __shared__ float Ht[E * E];     // Ht[e][f] = H_w[f][e]
    __shared__ float h_l[NSLOT * E];
    __shared__ float q_l[E], u_l[E];
    __shared__ float partA[80];
    __shared__ float d_l[NSLOT], p_l[NSLOT];
    const int tid = threadIdx.x;
    const int b   = blockIdx.x;

    for (int idx = tid; idx < E * E; idx += 128) {
        int r = idx / E, e = idx % E;
        Ht[e * E + r] = H_w[r * E + e];
    }
    for (int idx = tid; idx < NSLOT * E; idx += 128)
        h_l[idx] = h_final[(size_t)b * NSLOT * E + idx];
    if (tid < E) q_l[tid] = q_all[(size_t)b * E + tid];
    __syncthreads();

    if (tid < 80) {
        int n = tid / 4, j = tid % 4;
        float a = 0.f;
        for (int k = 0; k < 25; ++k) { int e = j * 25 + k; a += h_l[n * E + e] * q_l[e]; }
        partA[tid] = a;
    }
    __syncthreads();
    if (tid == 0) {
        float m = -1e30f;
        for (int n = 0; n < NSLOT; ++n) {
            float d = partA[n*4] + partA[n*4+1] + partA[n*4+2] + partA[n*4+3];
            d_l[n] = d; m = fmaxf(m, d);
        }
        float s = 0.f;
        for (int n = 0; n < NSLOT; ++n) { float e2 = expf(d_l[n] - m); p_l[n] = e2; s += e2; }
        float inv = 1.f / s;
        for (int n = 0; n < NSLOT; ++n) p_l[n] *= inv;
    }
    __syncthreads();
    if (tid < E) {
        float u = 0.f;
        for (int n = 0; n < NSLOT; ++n) u += p_l[n] * h_l[n * E + tid];
        u_l[tid] = u;
    }
    __syncthreads();
    if (tid < E) {
        float acc = q_l[tid] + H_b[tid];
        for (int e = 0; e < E; ++e) acc += u_l[e] * Ht[e * E + tid];
        const float ao = a_out[0];
        py_all[(size_t)b * E + tid] = acc >= 0.f ? acc : ao * acc;
    }
}

// ---------------------------------------------------------------------------
// Phase 4: out = py @ R_w^T + R_b.  M=512, N=32000, K=100. 64x64 tiles.
// ---------------------------------------------------------------------------
#define BT  64
#define VT  64
#define LDT 101
__global__ __launch_bounds__(256, 2) void k_out(
    const float* __restrict__ py_all, const float* __restrict__ R_w,
    const float* __restrict__ R_b, float* __restrict__ out)
{
    __shared__ float pt[BT * LDT];
    __shared__ float rt[VT * LDT];
    const int tid = threadIdx.x;
    const int v0 = blockIdx.x * VT;
    const int b0 = blockIdx.y * BT;

    for (int idx = tid; idx < BT * E; idx += 256) {
        int r = idx / E, e = idx % E;
        pt[r * LDT + e] = py_all[(size_t)(b0 + r) * E + e];
    }
    for (int idx = tid; idx < VT * E; idx += 256) {
        int r = idx / E, e = idx % E;
        rt[r * LDT + e] = R_w[(size_t)(v0 + r) * E + e];
    }
    __syncthreads();

    const int tv = tid % 16, tb = tid / 16;
    const int vl = tv * 4, bl = tb * 4;
    float acc[4][4] = {};
    for (int e = 0; e < E; ++e) {
        float pv[4], rv[4];
        #pragma unroll
        for (int i = 0; i < 4; ++i) pv[i] = pt[(bl + i) * LDT + e];
        #pragma unroll
        for (int j = 0; j < 4; ++j) rv[j] = rt[(vl + j) * LDT + e];
        #pragma unroll
        for (int i = 0; i < 4; ++i)
            #pragma unroll
            for (int j = 0; j < 4; ++j) acc[i][j] += pv[i] * rv[j];
    }
    float4 rb;
    rb.x = R_b[v0 + vl];     rb.y = R_b[v0 + vl + 1];
    rb.z = R_b[v0 + vl + 2]; rb.w = R_b[v0 + vl + 3];
    #pragma unroll
    for (int i = 0; i < 4; ++i) {
        float4 o;
        o.x = acc[i][0] + rb.x; o.y = acc[i][1] + rb.y;
        o.z = acc[i][2] + rb.z; o.w = acc[i][3] + rb.w;
        *reinterpret_cast<float4*>(&out[(size_t)(b0 + bl + i) * VV + v0 + vl]) = o;
    }
}

// ---------------------------------------------------------------------------
extern "C" void kernel_launch(void* const* d_in, const int* in_sizes, int n_in,
                              void* d_out, int out_size, void* d_ws, size_t ws_size,
                              hipStream_t stream)
{
    const float* in_data = (const float*)d_in[0];
    const float* f       = (const float*)d_in[1];
    const float* h0      = (const float*)d_in[2];
    const float* w_mem   = (const float*)d_in[3];
    const float* U_w     = (const float*)d_in[4];
    const float* V_w     = (const float*)d_in[5];
    const float* W_w     = (const float*)d_in[6];
    const float* a_dm    = (const float*)d_in[7];
    const float* H_w     = (const float*)d_in[8];
    const float* H_b     = (const float*)d_in[9];
    const float* R_w     = (const float*)d_in[10];
    const float* R_b     = (const float*)d_in[11];
    const float* a_out   = (const float*)d_in[12];
    float* out = (float*)d_out;

    float* ws      = (float*)d_ws;
    float* s_all   = ws;                    // 100*512*100 = 5,120,000
    float* sW_all  = s_all  + 5120000;      // 5,120,000
    float* q_all   = sW_all + 5120000;      // 51,200
    float* h_final = q_all  + 51200;        // 1,024,000
    float* py_all  = h_final + 1024000;     // 51,200   (total ~45.5 MB)

    k_prep<<<BB, 256, 0, stream>>>(in_data, f, W_w, s_all, sW_all, q_all);
    k_scan<<<BB, 256, 0, stream>>>(h0, w_mem, U_w, V_w, a_dm, s_all, sW_all, h_final);
    k_attn<<<BB, 128, 0, stream>>>(h_final, q_all, H_w, H_b, a_out, py_all);
    k_out<<<dim3(VV / VT, BB / BT), 256, 0, stream>>>(py_all, R_w, R_b, out);
}

// Round 2
// 777.465 us; speedup vs baseline: 1.1846x; 1.1846x over previous
//
#include <hip/hip_runtime.h>
#include <hip/hip_bf16.h>

#define E      100
#define NSLOT  20
#define BB     512
#define TT     1005
#define NFULL  100
#define LL     10
#define REST   5
#define VV     32000

typedef _Float16 f16x8 __attribute__((ext_vector_type(8)));
typedef float    f32x16 __attribute__((ext_vector_type(16)));

// ---------------------------------------------------------------------------
// Phase 1: infos (s_all, t-major), sW_all = infos @ W_w^T, q_all
// ---------------------------------------------------------------------------
__global__ __launch_bounds__(256, 2) void k_prep(
    const float* __restrict__ in_data, const float* __restrict__ f,
    const float* __restrict__ W_w,
    float* __restrict__ s_all, float* __restrict__ sW_all, float* __restrict__ q_all)
{
    __shared__ float Wt[E * E];   // Wt[e][fc] = W_w[fc][e]
    __shared__ float f_l[LL * E];
    __shared__ float s_l[2 * E];
    const int tid = threadIdx.x;
    const int b   = blockIdx.x;

    for (int idx = tid; idx < E * E; idx += 256) {
        int r = idx / E, e = idx % E;
        Wt[e * E + r] = W_w[r * E + e];
    }
    for (int idx = tid; idx < LL * E; idx += 256) f_l[idx] = f[idx];
    __syncthreads();

    const size_t base = (size_t)b * TT * E;
    for (int n = 0; n < NFULL; n += 2) {
        if (tid < 2 * E) {
            int e = tid % E, w = tid / E;
            int nn = n + w;
            float a = 0.f;
            #pragma unroll
            for (int l = 0; l < LL; ++l)
                a += f_l[l * E + e] * in_data[base + (size_t)(nn * LL + l) * E + e];
            s_l[w * E + e] = a;
            s_all[((size_t)nn * BB + b) * E + e] = a;
        }
        __syncthreads();
        if (tid < 2 * E) {
            int fc = tid % E, w = tid / E;
            float a = 0.f;
            for (int e = 0; e < E; ++e) a += Wt[e * E + fc] * s_l[w * E + e];
            sW_all[((size_t)(n + w) * BB + b) * E + fc] = a;
        }
        __syncthreads();
    }
    if (tid < E) {
        float a = 0.f;
        #pragma unroll
        for (int l = 0; l < REST; ++l)
            a += f_l[l * E + tid] * in_data[base + (size_t)(NFULL * LL + l) * E + tid];
        q_all[(size_t)b * E + tid] = a;
    }
}

// ---------------------------------------------------------------------------
// Phase 2: recurrent scan with f16 MFMA for U@h.
// One block per b. 4 waves; wave w owns f-columns [32w, 32w+32).
// U^T held in registers as MFMA B-fragments (loaded once).
// h: fp32 in LDS (LD=101) for gate/norm; f16 frag-major LDS for MFMA A.
// ---------------------------------------------------------------------------
__global__ __launch_bounds__(256, 2) void k_scan(
    const float* __restrict__ h0, const float* __restrict__ w_mem,
    const float* __restrict__ U_w, const float* __restrict__ V_w,
    const float* __restrict__ a_dm,
    const float* __restrict__ s_all, const float* __restrict__ sW_all,
    float* __restrict__ h_final)
{
    __shared__ float h32[NSLOT * 101];
    __shared__ __align__(16) _Float16 h16f[7 * 64 * 8];   // [ck][lane][8] A-frags
    __shared__ float wm[NSLOT * E];
    __shared__ float svb[2][128];
    __shared__ float swb[2][128];
    __shared__ float part[200];
    __shared__ float part2[200];
    __shared__ float gl[NSLOT];

    const int tid  = threadIdx.x;
    const int b    = blockIdx.x;
    const int lane = tid & 63;
    const int wv   = tid >> 6;
    const int col  = lane & 31;
    const int half = lane >> 5;
    const int fcol = wv * 32 + col;          // f (N-dim) this lane owns
    const float adm = a_dm[0];

    // ---- init: wm, h32 <- h0, zero h16f ----
    for (int i = tid; i < NSLOT * E; i += 256) {
        wm[i] = w_mem[i];
        int n = i / E, e = i - n * E;
        h32[n * 101 + e] = h0[i];
    }
    for (int i = tid; i < 7 * 64 * 4; i += 256)
        reinterpret_cast<int*>(h16f)[i] = 0;   // zero all 3584 halfs
    __syncthreads();

    // pack h0 -> h16f (scale 1)
    for (int idx = tid; idx < 260; idx += 256) {
        int row = idx / 13, e0 = (idx - row * 13) * 8;
        f16x8 v;
        #pragma unroll
        for (int k = 0; k < 8; ++k) {
            int e = e0 + k;
            v[k] = (_Float16)((e < E) ? h32[row * 101 + e] : 0.f);
        }
        int slot = (e0 >> 4) * 64 + row + ((e0 & 8) ? 32 : 0);
        *(f16x8*)&h16f[slot * 8] = v;
    }

    // B-fragments: B[k=e][n=f] = U_w[f][e], 7 chunks of K=16, held in VGPRs
    f16x8 Bf[7];
    #pragma unroll
    for (int ck = 0; ck < 7; ++ck) {
        #pragma unroll
        for (int j = 0; j < 8; ++j) {
            int e = 16 * ck + 8 * half + j;
            float v = (fcol < E && e < E) ? U_w[fcol * E + e] : 0.f;
            Bf[ck][j] = (_Float16)v;
        }
    }

    // VwC[r] = (w_mem @ V_w^T)[row(r)][fcol], in C-layout registers
    float VwC[16];
    #pragma unroll
    for (int r = 0; r < 16; ++r) {
        int row = (r & 3) + 8 * (r >> 2) + 4 * half;
        float a = 0.f;
        if (row < NSLOT && fcol < E) {
            for (int e = 0; e < E; e += 4) {
                const float4 w4 = *(const float4*)&wm[row * E + e];
                const float4 v4 = *(const float4*)&V_w[fcol * E + e];
                a += w4.x * v4.x + w4.y * v4.y + w4.z * v4.z + w4.w * v4.w;
            }
        }
        VwC[r] = a;
    }

    // t=0 sv/swv
    if (tid < 128) svb[0][tid] = (tid < E) ? s_all[(size_t)b * E + tid] : 0.f;
    else { int s = tid - 128; swb[0][s] = (s < E) ? sW_all[(size_t)b * E + s] : 0.f; }
    __syncthreads();

    for (int t = 0; t < NFULL; ++t) {
        const int p = t & 1;
        const float* __restrict__ sv = svb[p];
        const float* __restrict__ sw = swb[p];

        // gate partials: d[n] = sum_e (h+wm)[n][e]*sv[e]
        if (tid < 200) {
            int n = tid / 10, j = tid - n * 10;
            float a = 0.f;
            #pragma unroll
            for (int k = 0; k < 10; ++k) {
                int e = j * 10 + k;
                a += (h32[n * 101 + e] + wm[n * E + e]) * sv[e];
            }
            part[tid] = a;
        }
        // prefetch next step's sv/sW into registers (latency hidden by MFMA phase)
        float nf = 0.f;
        if (t + 1 < NFULL) {
            if (tid < E) nf = s_all[((size_t)(t + 1) * BB + b) * E + tid];
            else if (tid >= 128 && tid < 128 + E)
                nf = sW_all[((size_t)(t + 1) * BB + b) * E + (tid - 128)];
        }
        __syncthreads();                                   // A: part ready

        if (tid < NSLOT) {
            float d = 0.f;
            #pragma unroll
            for (int j = 0; j < 10; ++j) d += part[tid * 10 + j];
            gl[tid] = 1.f / (1.f + expf(-d));
        }

        // MFMA: cand = h @ U^T (+VwC init), fp32 accumulate
        f32x16 acc;
        #pragma unroll
        for (int r = 0; r < 16; ++r) acc[r] = VwC[r];
        #pragma unroll
        for (int ck = 0; ck < 7; ++ck) {
            f16x8 a = *(const f16x8*)&h16f[(ck * 64 + lane) * 8];
            acc = __builtin_amdgcn_mfma_f32_32x32x16_f16(a, Bf[ck], acc, 0, 0, 0);
        }
        const float swf = sw[fcol & 127];
        __syncthreads();                                   // B: gl ready

        // epilogue: prelu, gate, h += g*cand (unnormalized write)
        #pragma unroll
        for (int r = 0; r < 16; ++r) {
            int row = (r & 3) + 8 * (r >> 2) + 4 * half;
            if (row < NSLOT && fcol < E) {
                float c = acc[r] + swf;
                c = (c >= 0.f) ? c : adm * c;
                h32[row * 101 + fcol] += gl[row] * c;
            }
        }
        __syncthreads();                                   // C: h_new ready

        if (tid < 200) {
            int n = tid / 10, j = tid - n * 10;
            float a = 0.f;
            #pragma unroll
            for (int k = 0; k < 10; ++k) { float v = h32[n * 101 + j * 10 + k]; a += v * v; }
            part2[tid] = a;
        }
        __syncthreads();                                   // D: sq-partials ready

        // normalize + pack to f16 frags + commit prefetched sv/sW
        for (int idx = tid; idx < 260; idx += 256) {
            int row = idx / 13, e0 = (idx - row * 13) * 8;
            float s2 = 0.f;
            #pragma unroll
            for (int k = 0; k < 10; ++k) s2 += part2[row * 10 + k];
            float rin = rsqrtf(s2);
            f16x8 v;
            #pragma unroll
            for (int k = 0; k < 8; ++k) {
                int e = e0 + k;
                float hv = (e < E) ? h32[row * 101 + e] * rin : 0.f;
                if (e < E) h32[row * 101 + e] = hv;
                v[k] = (_Float16)hv;
            }
            int slot = (e0 >> 4) * 64 + row + ((e0 & 8) ? 32 : 0);
            *(f16x8*)&h16f[slot * 8] = v;
        }
        if (t + 1 < NFULL) {
            int pn = p ^ 1;
            if (tid < 128) svb[pn][tid] = nf;
            else swb[pn][tid - 128] = nf;
        }
        __syncthreads();                                   // E: h norm + frags ready
    }

    for (int i = tid; i < NSLOT * E; i += 256) {
        int n = i / E, e = i - n * E;
        h_final[(size_t)b * NSLOT * E + i] = h32[n * 101 + e];
    }
}

// ---------------------------------------------------------------------------
// Phase 3: attention over entities + y -> prelu(y) (py_all).
// ---------------------------------------------------------------------------
__global__ __launch_bounds__(128, 2) void k_attn(
    const float* __restrict__ h_final, const float* __restrict__ q_all,
    const float* __restrict__ H_w, const float* __restrict__ H_b,
    const float* __restrict__ a_out, float* __restrict__ py_all)
{
    __shared__ float Ht[E * E];
    __shared__ float h_l[NSLOT * E];
    __shared__ float q_l[E], u_l[E];
    __shared__ float partA[80];
    __shared__ float d_l[NSLOT], p_l[NSLOT];
    const int tid = threadIdx.x;
    const int b   = blockIdx.x;

    for (int idx = tid; idx < E * E; idx += 128) {
        int r = idx / E, e = idx % E;
        Ht[e * E + r] = H_w[r * E + e];
    }
    for (int idx = tid; idx < NSLOT * E; idx += 128)
        h_l[idx] = h_final[(size_t)b * NSLOT * E + idx];
    if (tid < E) q_l[tid] = q_all[(size_t)b * E + tid];
    __syncthreads();

    if (tid < 80) {
        int n = tid / 4, j = tid % 4;
        float a = 0.f;
        for (int k = 0; k < 25; ++k) { int e = j * 25 + k; a += h_l[n * E + e] * q_l[e]; }
        partA[tid] = a;
    }
    __syncthreads();
    if (tid == 0) {
        float m = -1e30f;
        for (int n = 0; n < NSLOT; ++n) {
            float d = partA[n*4] + partA[n*4+1] + partA[n*4+2] + partA[n*4+3];
            d_l[n] = d; m = fmaxf(m, d);
        }
        float s = 0.f;
        for (int n = 0; n < NSLOT; ++n) { float e2 = expf(d_l[n] - m); p_l[n] = e2; s += e2; }
        float inv = 1.f / s;
        for (int n = 0; n < NSLOT; ++n) p_l[n] *= inv;
    }
    __syncthreads();
    if (tid < E) {
        float u = 0.f;
        for (int n = 0; n < NSLOT; ++n) u += p_l[n] * h_l[n * E + tid];
        u_l[tid] = u;
    }
    __syncthreads();
    if (tid < E) {
        float acc = q_l[tid] + H_b[tid];
        for (int e = 0; e < E; ++e) acc += u_l[e] * Ht[e * E + tid];
        const float ao = a_out[0];
        py_all[(size_t)b * E + tid] = acc >= 0.f ? acc : ao * acc;
    }
}

// ---------------------------------------------------------------------------
// Phase 4: out = py @ R_w^T + R_b.  M=512, N=32000, K=100.
// ---------------------------------------------------------------------------
#define BT  64
#define VT  64
#define LDT 101
__global__ __launch_bounds__(256, 2) void k_out(
    const float* __restrict__ py_all, const float* __restrict__ R_w,
    const float* __restrict__ R_b, float* __restrict__ out)
{
    __shared__ float pt[BT * LDT];
    __shared__ float rt[VT * LDT];
    const int tid = threadIdx.x;
    const int v0 = blockIdx.x * VT;
    const int b0 = blockIdx.y * BT;

    for (int idx = tid; idx < BT * E; idx += 256) {
        int r = idx / E, e = idx % E;
        pt[r * LDT + e] = py_all[(size_t)(b0 + r) * E + e];
    }
    for (int idx = tid; idx < VT * E; idx += 256) {
        int r = idx / E, e = idx % E;
        rt[r * LDT + e] = R_w[(size_t)(v0 + r) * E + e];
    }
    __syncthreads();

    const int tv = tid % 16, tb = tid / 16;
    const int vl = tv * 4, bl = tb * 4;
    float acc[4][4] = {};
    for (int e = 0; e < E; ++e) {
        float pv[4], rv[4];
        #pragma unroll
        for (int i = 0; i < 4; ++i) pv[i] = pt[(bl + i) * LDT + e];
        #pragma unroll
        for (int j = 0; j < 4; ++j) rv[j] = rt[(vl + j) * LDT + e];
        #pragma unroll
        for (int i = 0; i < 4; ++i)
            #pragma unroll
            for (int j = 0; j < 4; ++j) acc[i][j] += pv[i] * rv[j];
    }
    float4 rb;
    rb.x = R_b[v0 + vl];     rb.y = R_b[v0 + vl + 1];
    rb.z = R_b[v0 + vl + 2]; rb.w = R_b[v0 + vl + 3];
    #pragma unroll
    for (int i = 0; i < 4; ++i) {
        float4 o;
        o.x = acc[i][0] + rb.x; o.y = acc[i][1] + rb.y;
        o.z = acc[i][2] + rb.z; o.w = acc[i][3] + rb.w;
        *reinterpret_cast<float4*>(&out[(size_t)(b0 + bl + i) * VV + v0 + vl]) = o;
    }
}

// ---------------------------------------------------------------------------
extern "C" void kernel_launch(void* const* d_in, const int* in_sizes, int n_in,
                              void* d_out, int out_size, void* d_ws, size_t ws_size,
                              hipStream_t stream)
{
    const float* in_data = (const float*)d_in[0];
    const float* f       = (const float*)d_in[1];
    const float* h0      = (const float*)d_in[2];
    const float* w_mem   = (const float*)d_in[3];
    const float* U_w     = (const float*)d_in[4];
    const float* V_w     = (const float*)d_in[5];
    const float* W_w     = (const float*)d_in[6];
    const float* a_dm    = (const float*)d_in[7];
    const float* H_w     = (const float*)d_in[8];
    const float* H_b     = (const float*)d_in[9];
    const float* R_w     = (const float*)d_in[10];
    const float* R_b     = (const float*)d_in[11];
    const float* a_out   = (const float*)d_in[12];
    float* out = (float*)d_out;

    float* ws      = (float*)d_ws;
    float* s_all   = ws;
    float* sW_all  = s_all  + 5120000;
    float* q_all   = sW_all + 5120000;
    float* h_final = q_all  + 51200;
    float* py_all  = h_final + 1024000;

    k_prep<<<BB, 256, 0, stream>>>(in_data, f, W_w, s_all, sW_all, q_all);
    k_scan<<<BB, 256, 0, stream>>>(h0, w_mem, U_w, V_w, a_dm, s_all, sW_all, h_final);
    k_attn<<<BB, 128, 0, stream>>>(h_final, q_all, H_w, H_b, a_out, py_all);
    k_out<<<dim3(VV / VT, BB / BT), 256, 0, stream>>>(py_all, R_w, R_b, out);
}

// Round 3
// 676.125 us; speedup vs baseline: 1.3621x; 1.1499x over previous
//
#include <hip/hip_runtime.h>
#include <hip/hip_bf16.h>

#define E      100
#define E2     112
#define NSLOT  20
#define BB     512
#define TT     1005
#define NFULL  100
#define LL     10
#define REST   5
#define VV     32000

typedef _Float16 f16x8 __attribute__((ext_vector_type(8)));
typedef _Float16 f16x4 __attribute__((ext_vector_type(4)));
typedef float    f32x16 __attribute__((ext_vector_type(16)));

// ---------------------------------------------------------------------------
// k_cvt: R_w -> R16 [32000][112] f16 (K-padded), and Wm16 [128][112] f16
// (rows 0..99 = W_w, 100..119 = w_mem, 120..127 = 0).
// ---------------------------------------------------------------------------
__global__ __launch_bounds__(256) void k_cvt(
    const float* __restrict__ R_w, const float* __restrict__ W_w,
    const float* __restrict__ w_mem,
    _Float16* __restrict__ R16, _Float16* __restrict__ Wm16)
{
    const int gid = blockIdx.x * 256 + threadIdx.x;   // 3500*256 = 896000 exact
    {
        int v = gid / 28, e4 = gid % 28;
        f16x4 o;
        if (e4 < 25) {
            float4 x = *(const float4*)&R_w[(size_t)v * E + e4 * 4];
            o[0] = (_Float16)x.x; o[1] = (_Float16)x.y;
            o[2] = (_Float16)x.z; o[3] = (_Float16)x.w;
        } else { o[0] = o[1] = o[2] = o[3] = (_Float16)0.f; }
        *(f16x4*)&R16[(size_t)v * E2 + e4 * 4] = o;
    }
    if (gid < 128 * 28) {
        int j = gid / 28, e4 = gid % 28;
        f16x4 o; o[0] = o[1] = o[2] = o[3] = (_Float16)0.f;
        if (e4 < 25 && j < 120) {
            float4 x = (j < 100) ? *(const float4*)&W_w[j * E + e4 * 4]
                                 : *(const float4*)&w_mem[(j - 100) * E + e4 * 4];
            o[0] = (_Float16)x.x; o[1] = (_Float16)x.y;
            o[2] = (_Float16)x.z; o[3] = (_Float16)x.w;
        }
        *(f16x4*)&Wm16[j * E2 + e4 * 4] = o;
    }
}

// ---------------------------------------------------------------------------
// k_prep: streaming. s16[(n*512+b)*112 + e] = sum_l f[l][e]*x[b][10n+l][e],
// e>=100 zero-padded. q_all fp32. No barriers in the hot loop.
// ---------------------------------------------------------------------------
__global__ __launch_bounds__(256, 2) void k_prep(
    const float* __restrict__ in_data, const float* __restrict__ f,
    _Float16* __restrict__ s16, float* __restrict__ q_all)
{
    __shared__ float4 f4s[250];
    const int tid = threadIdx.x;
    const int b   = blockIdx.x;
    if (tid < 250) f4s[tid] = ((const float4*)f)[tid];
    __syncthreads();

    const size_t base = (size_t)b * TT * E;
    for (int idx = tid; idx < 2500; idx += 256) {
        int n = idx / 25, e4 = idx - n * 25;
        float4 a; a.x = a.y = a.z = a.w = 0.f;
        const float* xp = in_data + base + (size_t)(n * LL) * E + e4 * 4;
        #pragma unroll
        for (int l = 0; l < LL; ++l) {
            float4 x = *(const float4*)(xp + l * E);
            float4 fv = f4s[l * 25 + e4];
            a.x += fv.x * x.x; a.y += fv.y * x.y;
            a.z += fv.z * x.z; a.w += fv.w * x.w;
        }
        f16x4 o;
        o[0] = (_Float16)a.x; o[1] = (_Float16)a.y;
        o[2] = (_Float16)a.z; o[3] = (_Float16)a.w;
        *(f16x4*)&s16[((size_t)n * BB + b) * E2 + e4 * 4] = o;
    }
    // zero-pad e=100..111 for all 100 rows of this b
    for (int idx = tid; idx < 600; idx += 256) {
        int n = idx / 6, k = idx - n * 6;
        ((unsigned int*)s16)[(((size_t)n * BB + b) * E2 + 100) / 2 + k] = 0u;
    }
    if (tid < E) {
        const float* fp = (const float*)f4s;
        float a = 0.f;
        #pragma unroll
        for (int l = 0; l < REST; ++l)
            a += fp[l * E + tid] * in_data[base + (size_t)(NFULL * LL + l) * E + tid];
        q_all[(size_t)b * E + tid] = a;
    }
}

// ---------------------------------------------------------------------------
// k_mm: sws16[row][j] = s16[row][:] @ Wm16[j][:]  (row = t*512+b, j<128)
// M=51200, N=128, K=112. f16 MFMA, frag-major LDS staging.
// ---------------------------------------------------------------------------
__global__ __launch_bounds__(256, 2) void k_mm(
    const _Float16* __restrict__ s16, const _Float16* __restrict__ Wm16,
    _Float16* __restrict__ sws16)
{
    __shared__ __align__(16) _Float16 AF[14 * 128 * 8];
    __shared__ __align__(16) _Float16 BF[14 * 128 * 8];
    const int tid  = threadIdx.x;
    const int mb   = blockIdx.x;
    const int lane = tid & 63;
    const int wv   = tid >> 6;
    const int half = lane >> 5;
    const int jt   = wv * 32 + (lane & 31);

    for (int idx = tid; idx < 128 * 14; idx += 256) {
        int m = idx / 14, c8 = idx - m * 14;
        *(f16x8*)&AF[(c8 * 128 + m) * 8] =
            *(const f16x8*)&s16[((size_t)mb * 128 + m) * E2 + c8 * 8];
        *(f16x8*)&BF[(c8 * 128 + m) * 8] =
            *(const f16x8*)&Wm16[m * E2 + c8 * 8];
    }
    __syncthreads();

    f16x8 Bfr[7];
    #pragma unroll
    for (int ck = 0; ck < 7; ++ck)
        Bfr[ck] = *(const f16x8*)&BF[((ck * 2 + half) * 128 + jt) * 8];

    #pragma unroll
    for (int Mt = 0; Mt < 4; ++Mt) {
        f32x16 acc;
        #pragma unroll
        for (int r = 0; r < 16; ++r) acc[r] = 0.f;
        #pragma unroll
        for (int ck = 0; ck < 7; ++ck) {
            f16x8 a = *(const f16x8*)&AF[((ck * 2 + half) * 128 + 32 * Mt + (lane & 31)) * 8];
            acc = __builtin_amdgcn_mfma_f32_32x32x16_f16(a, Bfr[ck], acc, 0, 0, 0);
        }
        #pragma unroll
        for (int r = 0; r < 16; ++r) {
            int row = 32 * Mt + (r & 3) + 8 * (r >> 2) + 4 * half;
            sws16[((size_t)mb * 128 + row) * 128 + jt] = (_Float16)acc[r];
        }
    }
}

// ---------------------------------------------------------------------------
// k_scan: 3 barriers/step. h in C-layout registers; deferred normalization
// (store un-normalized R; rn folds into epilogue since MFMA is row-linear).
// Gate+norm partials computed from A-layout f16 frags, fused reduction.
// ---------------------------------------------------------------------------
__global__ __launch_bounds__(256, 2) void k_scan(
    const float* __restrict__ h0, const float* __restrict__ w_mem,
    const float* __restrict__ U_w, const float* __restrict__ V_w,
    const float* __restrict__ a_dm,
    const _Float16* __restrict__ s16, const _Float16* __restrict__ sws16,
    float* __restrict__ h_final)
{
    __shared__ __align__(16) _Float16 h16f[7 * 64 * 8];      // A-frags of R
    __shared__ __align__(16) _Float16 svL[2][128];
    __shared__ __align__(16) _Float16 swsL[2][128];
    __shared__ __align__(16) float2   d8[32 * 8];            // (gate, norm) partials
    __shared__ __align__(8)  float2   grn[32];               // (g, rn) per row

    const int tid  = threadIdx.x;
    const int b    = blockIdx.x;
    const int lane = tid & 63;
    const int wv   = tid >> 6;
    const int col  = lane & 31;
    const int half = lane >> 5;
    const int fcol = wv * 32 + col;
    const int nrow = lane & 31;          // n owned in A-layout
    const int nval = half ? 8 : 12;      // valid r count (rows<20)
    const float adm = a_dm[0];

    // ---- one-time setup ----
    f16x8 Bf[7];                         // U^T B-frags
    #pragma unroll
    for (int ck = 0; ck < 7; ++ck) {
        #pragma unroll
        for (int j = 0; j < 8; ++j) {
            int e = 16 * ck + 8 * half + j;
            Bf[ck][j] = (_Float16)((fcol < E && e < E) ? U_w[fcol * E + e] : 0.f);
        }
    }
    float VwC[16], hC[16];
    #pragma unroll
    for (int r = 0; r < 16; ++r) { VwC[r] = 0.f; hC[r] = 0.f; }
    for (int r = 0; r < nval; ++r) {
        int row = (r & 3) + 8 * (r >> 2) + 4 * half;
        if (fcol < E) {
            float a = 0.f;
            for (int e4 = 0; e4 < 25; ++e4) {
                float4 w4 = *(const float4*)&w_mem[row * E + e4 * 4];
                float4 v4 = *(const float4*)&V_w[fcol * E + e4 * 4];
                a += w4.x * v4.x + w4.y * v4.y + w4.z * v4.z + w4.w * v4.w;
            }
            VwC[r] = a;
            hC[r]  = h0[row * E + fcol];
        }
    }
    // initial pack of R_0 = h0 into A-frags
    for (int r = 0; r < nval; ++r) {
        int row = (r & 3) + 8 * (r >> 2) + 4 * half;
        if (fcol < E2) {
            int slot = (fcol >> 4) * 64 + ((fcol >> 3) & 1) * 32 + row;
            h16f[slot * 8 + (fcol & 7)] = (_Float16)hC[r];
        }
    }
    // t=0 sv/sws
    if (tid < E2) svL[0][tid] = s16[(size_t)b * E2 + tid];
    else if (tid >= 128) swsL[0][tid - 128] = sws16[(size_t)b * 128 + (tid - 128)];
    __syncthreads();

    const unsigned short* s16u  = (const unsigned short*)s16;
    const unsigned short* sws16u = (const unsigned short*)sws16;

    for (int t = 0; t < NFULL; ++t) {
        const int p = t & 1;

        // ---- phase 1: A-frags, gate+norm partials, MFMA, prefetch ----
        unsigned short nsv = 0, nsw = 0;
        if (t + 1 < NFULL) {
            if (tid < E2) nsv = s16u[((size_t)(t + 1) * BB + b) * E2 + tid];
            else if (tid >= 128) nsw = sws16u[((size_t)(t + 1) * BB + b) * 128 + (tid - 128)];
        }
        f16x8 hA[7];
        float gp = 0.f, np = 0.f;
        #pragma unroll
        for (int ck = 0; ck < 7; ++ck) {
            hA[ck] = *(const f16x8*)&h16f[(ck * 64 + lane) * 8];
            f16x8 sv8 = *(const f16x8*)&svL[p][16 * ck + 8 * half];
            #pragma unroll
            for (int j = 0; j < 8; ++j) {
                float hv = (float)hA[ck][j];
                gp += hv * (float)sv8[j];
                np += hv * hv;
            }
        }
        d8[nrow * 8 + (wv * 2 + half)] = make_float2(gp, np);

        f32x16 acc;
        #pragma unroll
        for (int r = 0; r < 16; ++r) acc[r] = 0.f;
        #pragma unroll
        for (int ck = 0; ck < 7; ++ck)
            acc = __builtin_amdgcn_mfma_f32_32x32x16_f16(hA[ck], Bf[ck], acc, 0, 0, 0);
        __syncthreads();                                      // B1

        // ---- narrow reduce: g and rn per row ----
        if (tid < 32) {
            float g = 0.f, rn = 0.f;
            if (tid < NSLOT) {
                const float4* dp = (const float4*)&d8[tid * 8];
                float4 a = dp[0], c = dp[1], e4 = dp[2], f4 = dp[3];
                float graw = (a.x + a.z + c.x + c.z + e4.x + e4.z + f4.x + f4.z) * 0.25f;
                float s2   = (a.y + a.w + c.y + c.w + e4.y + e4.w + f4.y + f4.w) * 0.25f;
                rn = (t == 0) ? 1.f : rsqrtf(s2);
                float d = rn * graw + (float)swsL[p][100 + tid];
                g = 1.f / (1.f + __expf(-d));
            }
            grn[tid] = make_float2(g, rn);
        }
        __syncthreads();                                      // B2

        // ---- phase 2: epilogue, pack, commit prefetch ----
        const float swf = (fcol < E) ? (float)swsL[p][fcol] : 0.f;
        for (int r = 0; r < nval; ++r) {
            int row = (r & 3) + 8 * (r >> 2) + 4 * half;
            float2 gr = grn[row];
            float c = fmaf(gr.y, acc[r], VwC[r] + swf);
            c = (c >= 0.f) ? c : adm * c;
            float hnew = fmaf(gr.y, hC[r], gr.x * c);
            hC[r] = hnew;
            if (fcol < E2) {
                int slot = (fcol >> 4) * 64 + ((fcol >> 3) & 1) * 32 + row;
                h16f[slot * 8 + (fcol & 7)] = (_Float16)hnew;
            }
        }
        if (t + 1 < NFULL) {
            int pn = p ^ 1;
            if (tid < E2) ((unsigned short*)svL[pn])[tid] = nsv;
            else if (tid >= 128) ((unsigned short*)swsL[pn])[tid - 128] = nsw;
        }
        __syncthreads();                                      // B3
    }

    // ---- final normalization of R_100 ----
    {
        float np = 0.f;
        #pragma unroll
        for (int ck = 0; ck < 7; ++ck) {
            f16x8 hA = *(const f16x8*)&h16f[(ck * 64 + lane) * 8];
            #pragma unroll
            for (int j = 0; j < 8; ++j) { float hv = (float)hA[j]; np += hv * hv; }
        }
        d8[nrow * 8 + (wv * 2 + half)].y = np;
        __syncthreads();
        if (tid < 32) {
            float rn = 0.f;
            if (tid < NSLOT) {
                const float4* dp = (const float4*)&d8[tid * 8];
                float4 a = dp[0], c = dp[1], e4 = dp[2], f4 = dp[3];
                float s2 = (a.y + a.w + c.y + c.w + e4.y + e4.w + f4.y + f4.w) * 0.25f;
                rn = rsqrtf(s2);
            }
            grn[tid] = make_float2(0.f, rn);
        }
        __syncthreads();
        if (fcol < E) {
            for (int r = 0; r < nval; ++r) {
                int row = (r & 3) + 8 * (r >> 2) + 4 * half;
                h_final[(size_t)b * NSLOT * E + row * E + fcol] = grn[row].y * hC[r];
            }
        }
    }
}

// ---------------------------------------------------------------------------
// k_attn: scores->softmax->u->y->prelu->py16 (padded to 112). One block per b.
// ---------------------------------------------------------------------------
__global__ __launch_bounds__(256, 2) void k_attn(
    const float* __restrict__ h_final, const float* __restrict__ q_all,
    const float* __restrict__ H_w, const float* __restrict__ H_b,
    const float* __restrict__ a_out, _Float16* __restrict__ py16)
{
    __shared__ float Hl[E * 101];
    __shared__ float h_l[NSLOT * E];
    __shared__ float q_l[E], u_l[E];
    __shared__ float part[200], party[200];
    __shared__ float dl[NSLOT], pl[NSLOT];
    const int tid = threadIdx.x;
    const int b   = blockIdx.x;

    for (int idx = tid; idx < E * E; idx += 256) {
        int fr = idx / E, e = idx - fr * E;
        Hl[fr * 101 + e] = H_w[idx];
    }
    for (int idx = tid; idx < NSLOT * E; idx += 256)
        h_l[idx] = h_final[(size_t)b * NSLOT * E + idx];
    if (tid < E) q_l[tid] = q_all[(size_t)b * E + tid];
    __syncthreads();

    if (tid < 200) {
        int n = tid / 10, j = tid - n * 10;
        float a = 0.f;
        #pragma unroll
        for (int k = 0; k < 10; ++k) { int e = j * 10 + k; a += h_l[n * E + e] * q_l[e]; }
        part[tid] = a;
    }
    __syncthreads();
    if (tid < NSLOT) {
        float d = 0.f;
        #pragma unroll
        for (int j = 0; j < 10; ++j) d += part[tid * 10 + j];
        dl[tid] = d;
    }
    __syncthreads();
    if (tid < NSLOT) {
        float m = -1e30f;
        for (int i = 0; i < NSLOT; ++i) m = fmaxf(m, dl[i]);
        float s = 0.f;
        for (int i = 0; i < NSLOT; ++i) s += __expf(dl[i] - m);
        pl[tid] = __expf(dl[tid] - m) / s;
    }
    __syncthreads();
    if (tid < E) {
        float u = 0.f;
        for (int n = 0; n < NSLOT; ++n) u += pl[n] * h_l[n * E + tid];
        u_l[tid] = u;
    }
    __syncthreads();
    if (tid < 200) {
        int fr = tid % E, hf = tid / E;
        float a = 0.f;
        for (int e = hf * 50; e < hf * 50 + 50; ++e) a += u_l[e] * Hl[fr * 101 + e];
        party[tid] = a;
    }
    __syncthreads();
    if (tid < E2) {
        if (tid < E) {
            float y = q_l[tid] + H_b[tid] + party[tid] + party[100 + tid];
            const float ao = a_out[0];
            y = (y >= 0.f) ? y : ao * y;
            py16[(size_t)b * E2 + tid] = (_Float16)y;
        } else py16[(size_t)b * E2 + tid] = (_Float16)0.f;
    }
}

// ---------------------------------------------------------------------------
// k_out: out = py @ R^T + R_b via f16 MFMA. Tiles 128(b) x 128(v), K=112.
// ---------------------------------------------------------------------------
__global__ __launch_bounds__(256, 2) void k_out(
    const _Float16* __restrict__ py16, const _Float16* __restrict__ R16,
    const float* __restrict__ R_b, float* __restrict__ out)
{
    __shared__ __align__(16) _Float16 AF[14 * 128 * 8];
    __shared__ __align__(16) _Float16 BF[14 * 128 * 8];
    const int tid  = threadIdx.x;
    const int vb   = blockIdx.x;          // 250
    const int mb   = blockIdx.y;          // 4
    const int lane = tid & 63;
    const int wv   = tid >> 6;
    const int half = lane >> 5;
    const int jt   = wv * 32 + (lane & 31);
    const int v0   = vb * 128;

    for (int idx = tid; idx < 128 * 14; idx += 256) {
        int m = idx / 14, c8 = idx - m * 14;
        *(f16x8*)&AF[(c8 * 128 + m) * 8] =
            *(const f16x8*)&py16[((size_t)mb * 128 + m) * E2 + c8 * 8];
        *(f16x8*)&BF[(c8 * 128 + m) * 8] =
            *(const f16x8*)&R16[(size_t)(v0 + m) * E2 + c8 * 8];
    }
    __syncthreads();

    f16x8 Bfr[7];
    #pragma unroll
    for (int ck = 0; ck < 7; ++ck)
        Bfr[ck] = *(const f16x8*)&BF[((ck * 2 + half) * 128 + jt) * 8];
    const float rbv = R_b[v0 + jt];

    #pragma unroll
    for (int Mt = 0; Mt < 4; ++Mt) {
        f32x16 acc;
        #pragma unroll
        for (int r = 0; r < 16; ++r) acc[r] = 0.f;
        #pragma unroll
        for (int ck = 0; ck < 7; ++ck) {
            f16x8 a = *(const f16x8*)&AF[((ck * 2 + half) * 128 + 32 * Mt + (lane & 31)) * 8];
            acc = __builtin_amdgcn_mfma_f32_32x32x16_f16(a, Bfr[ck], acc, 0, 0, 0);
        }
        #pragma unroll
        for (int r = 0; r < 16; ++r) {
            int row = 32 * Mt + (r & 3) + 8 * (r >> 2) + 4 * half;
            out[((size_t)mb * 128 + row) * VV + v0 + jt] = acc[r] + rbv;
        }
    }
}

// ---------------------------------------------------------------------------
extern "C" void kernel_launch(void* const* d_in, const int* in_sizes, int n_in,
                              void* d_out, int out_size, void* d_ws, size_t ws_size,
                              hipStream_t stream)
{
    const float* in_data = (const float*)d_in[0];
    const float* f       = (const float*)d_in[1];
    const float* h0      = (const float*)d_in[2];
    const float* w_mem   = (const float*)d_in[3];
    const float* U_w     = (const float*)d_in[4];
    const float* V_w     = (const float*)d_in[5];
    const float* W_w     = (const float*)d_in[6];
    const float* a_dm    = (const float*)d_in[7];
    const float* H_w     = (const float*)d_in[8];
    const float* H_b     = (const float*)d_in[9];
    const float* R_w     = (const float*)d_in[10];
    const float* R_b     = (const float*)d_in[11];
    const float* a_out   = (const float*)d_in[12];
    float* out = (float*)d_out;

    char* ws = (char*)d_ws;
    _Float16* s16    = (_Float16*)(ws);                       // 11,468,800 B
    _Float16* sws16  = (_Float16*)(ws + 11468800);            // 13,107,200 B
    _Float16* R16    = (_Float16*)(ws + 24576000);            //  7,168,000 B
    _Float16* Wm16   = (_Float16*)(ws + 31744000);            //     28,672 B
    float*    q_all  = (float*)   (ws + 31772672);            //    204,800 B
    float*    h_fin  = (float*)   (ws + 31977472);            //  4,096,000 B
    _Float16* py16   = (_Float16*)(ws + 36073472);            //    114,688 B

    k_cvt <<<3500, 256, 0, stream>>>(R_w, W_w, w_mem, R16, Wm16);
    k_prep<<<BB, 256, 0, stream>>>(in_data, f, s16, q_all);
    k_mm  <<<400, 256, 0, stream>>>(s16, Wm16, sws16);
    k_scan<<<BB, 256, 0, stream>>>(h0, w_mem, U_w, V_w, a_dm, s16, sws16, h_fin);
    k_attn<<<BB, 256, 0, stream>>>(h_fin, q_all, H_w, H_b, a_out, py16);
    k_out <<<dim3(VV / 128, 4), 256, 0, stream>>>(py16, R16, R_b, out);
}